// Round 1
// 1758.456 us; speedup vs baseline: 1.1820x; 1.1820x over previous
//
#include <hip/hip_runtime.h>
#include <hip/hip_bf16.h>
#include <math.h>

typedef __hip_bfloat16 bf16;
typedef __attribute__((ext_vector_type(8))) short short8;
typedef __attribute__((ext_vector_type(4))) float floatx4;
typedef __attribute__((ext_vector_type(4))) unsigned short ushortx4;

__device__ __forceinline__ float bfu2f(unsigned short u) {
    unsigned int w = ((unsigned int)u) << 16;
    float f;
    __builtin_memcpy(&f, &w, 4);
    return f;
}
__device__ __forceinline__ unsigned short f2bfu(float x) {
    bf16 b = __float2bfloat16(x);  // RNE
    unsigned short u;
    __builtin_memcpy(&u, &b, 2);
    return u;
}
// exact 3-way split: a = s0+s1+s2 + err, |err| <= 2^-27 |a|
__device__ __forceinline__ void split3(float a, unsigned short& s0,
                                       unsigned short& s1, unsigned short& s2) {
    s0 = f2bfu(a);
    float r1 = a - bfu2f(s0);   // exact (Sterbenz)
    s1 = f2bfu(r1);
    float r2 = r1 - bfu2f(s1);  // exact
    s2 = f2bfu(r2);
}

// global -> LDS direct copy, 16B per lane. LDS dest must be wave-uniform base.
typedef __attribute__((address_space(1))) unsigned int as1_u32;
typedef __attribute__((address_space(3))) unsigned int as3_u32;
__device__ __forceinline__ void gload16(const void* g, void* l) {
    __builtin_amdgcn_global_load_lds((const as1_u32*)g, (as3_u32*)l, 16, 0, 0);
}

// ---------------------------------------------------------------------------
// Weight transpose + 3-way bf16 split: W[Ktrue,Ntrue] fp32 -> 3 planes
// [Nalloc][Kpad] bf16, zero-filled for k in [Ktrue,Kpad) and n in [Ntrue,Nalloc).
// ---------------------------------------------------------------------------
__global__ __launch_bounds__(256) void wsplit_kernel(
    const float* __restrict__ W, unsigned short* __restrict__ out,
    int Ktrue, int Kpad, int Ntrue, int Nalloc)
{
    __shared__ float T[32][33];
    const int tx = threadIdx.x & 31, ty = threadIdx.x >> 5;
    const int k0 = blockIdx.x * 32, n0 = blockIdx.y * 32;
#pragma unroll
    for (int i = 0; i < 4; i++) {
        int k = k0 + ty + 8 * i, n = n0 + tx;
        T[ty + 8 * i][tx] = (k < Ktrue && n < Ntrue) ? W[(size_t)k * Ntrue + n] : 0.f;
    }
    __syncthreads();
    const size_t PS = (size_t)Nalloc * Kpad;
#pragma unroll
    for (int i = 0; i < 4; i++) {
        int n = n0 + ty + 8 * i, k = k0 + tx;
        if (n < Nalloc) {
            unsigned short h0, h1, h2;
            split3(T[tx][ty + 8 * i], h0, h1, h2);
            size_t base = (size_t)n * Kpad + k;
            out[0 * PS + base] = h0;
            out[1 * PS + base] = h1;
            out[2 * PS + base] = h2;
        }
    }
}

// ---------------------------------------------------------------------------
// Activation split: A[M,Ka] fp32 -> 3 bf16 planes [M][Kpad], zero-fill tail.
// ---------------------------------------------------------------------------
__global__ __launch_bounds__(256) void asplit_kernel(
    const float* __restrict__ A, unsigned short* __restrict__ out,
    int Ka, int Kpad, int M)
{
    const int kq = Kpad >> 2;
    const int n = M * kq;
    int idx = blockIdx.x * 256 + threadIdx.x;
    if (idx >= n) return;
    int row = idx / kq, c4 = idx - row * kq;
    const size_t PS = (size_t)M * Kpad;
    ushortx4 o0, o1, o2;
#pragma unroll
    for (int e = 0; e < 4; e++) {
        int col = c4 * 4 + e;
        float v = (col < Ka) ? A[(size_t)row * Ka + col] : 0.f;
        unsigned short a, b, c;
        split3(v, a, b, c);
        o0[e] = a; o1[e] = b; o2[e] = c;
    }
    size_t base = (size_t)row * Kpad + c4 * 4;
    *(ushortx4*)(out + base) = o0;
    *(ushortx4*)(out + PS + base) = o1;
    *(ushortx4*)(out + 2 * PS + base) = o2;
}

// ---------------------------------------------------------------------------
// Pre-split 6-product bf16 MFMA GEMM (fp32-equivalent):
//   C[M,N] = A @ B^T + bias, A planes [3][M][Kpad], B planes [3][Nb][Kpad].
// 128x128 tile, BK=32, 4 waves, per wave 4x4 of 16x16x32 MFMA.
// Staging via global_load_lds w=16, linear LDS dest + pre-swizzled source,
// XOR key (row>>1)&3 on 16B slots -> 2-way LDS read conflicts (free).
// LDS 48 KiB -> 3 blocks/CU.
// ---------------------------------------------------------------------------
__global__ __launch_bounds__(256, 3) void mfma_gemm2(
    const unsigned short* __restrict__ Apl,
    const unsigned short* __restrict__ Bpl,
    const float* __restrict__ bias, float* __restrict__ C,
    int M, int N, int Kpad, int Nb)
{
    __shared__ __align__(16) unsigned short As[3][128][32];
    __shared__ __align__(16) unsigned short Bs[3][128][32];

    const int tid = threadIdx.x;
    const int lane = tid & 63;
    const int wave = tid >> 6;
    const int wm = (wave & 1) * 64, wn = (wave >> 1) * 64;

    // XCD-aware bijective swizzle (all grids here are multiples of 8 blocks)
    const int gx = gridDim.x;
    const int nwg = gx * gridDim.y;
    const int id = blockIdx.y * gx + blockIdx.x;
    const int cpx = nwg >> 3;
    const int swz = (id & 7) * cpx + (id >> 3);
    const int bm = (swz / gx) * 128, bn = (swz % gx) * 128;

    const int l15 = lane & 15, q = lane >> 4;
    const size_t PSA = (size_t)M * Kpad;
    const size_t PSB = (size_t)Nb * Kpad;

    // staging geometry: 24 chunks per matrix, each 16 rows x 32 k (1 KiB).
    // lane covers row rb+(lane>>2), physical 16B slot lane&3; source slot
    // pre-swizzled so that read-side XOR recovers linear k.
    const int srow = lane >> 2;
    const int gslot = (lane & 3) ^ ((srow >> 1) & 3);
    const int rkey = (l15 >> 1) & 3;  // read-side XOR key (row bits [2:1])

    floatx4 acc[4][4] = {};

    for (int k0 = 0; k0 < Kpad; k0 += 32) {
        // ---- stage: 12 global_load_lds per wave (6 A-chunks + 6 B-chunks) ----
#pragma unroll
        for (int i = 0; i < 6; i++) {
            int j = wave * 6 + i;          // chunk id 0..23
            int p = j >> 3, rb = (j & 7) << 4;
            const unsigned short* sA = Apl + (size_t)p * PSA
                + (size_t)(bm + rb + srow) * Kpad + (k0 + gslot * 8);
            gload16(sA, &As[p][rb][0]);
            const unsigned short* sB = Bpl + (size_t)p * PSB
                + (size_t)(bn + rb + srow) * Kpad + (k0 + gslot * 8);
            gload16(sB, &Bs[p][rb][0]);
        }
        __syncthreads();  // compiler drains vmcnt before s_barrier

        // ---- fragments (swizzled read) + 6 products, shared accumulator ----
        short8 bfr[3][4];
#pragma unroll
        for (int p = 0; p < 3; p++)
#pragma unroll
            for (int ni = 0; ni < 4; ni++)
                bfr[p][ni] = *(const short8*)&Bs[p][wn + ni * 16 + l15][(q ^ rkey) * 8];
#pragma unroll
        for (int pa = 0; pa < 3; pa++) {
            short8 af[4];
#pragma unroll
            for (int mi = 0; mi < 4; mi++)
                af[mi] = *(const short8*)&As[pa][wm + mi * 16 + l15][(q ^ rkey) * 8];
#pragma unroll
            for (int pb = 0; pb + pa < 3; pb++) {
#pragma unroll
                for (int mi = 0; mi < 4; mi++)
#pragma unroll
                    for (int ni = 0; ni < 4; ni++)
                        acc[mi][ni] = __builtin_amdgcn_mfma_f32_16x16x32_bf16(
                            af[mi], bfr[pb][ni], acc[mi][ni], 0, 0, 0);
            }
        }
        __syncthreads();
    }

    // ---- epilogue: bias + store (C/D layout: col=lane&15, row=q*4+reg) ----
#pragma unroll
    for (int ni = 0; ni < 4; ni++) {
        int col = bn + wn + ni * 16 + l15;
        if (col >= N) continue;
        float bv = bias[col];
#pragma unroll
        for (int mi = 0; mi < 4; mi++) {
#pragma unroll
            for (int reg = 0; reg < 4; reg++) {
                int row = bm + wm + mi * 16 + q * 4 + reg;
                C[(size_t)row * N + col] = acc[mi][ni][reg] + bv;
            }
        }
    }
}

// ---------------------------------------------------------------------------
// OLD fused split-in-GEMM path (fallback when ws too small for pre-split).
// ---------------------------------------------------------------------------
template <bool AVEC, bool NG>
__global__ __launch_bounds__(256) void mfma_gemm(
    const float* __restrict__ A, const unsigned short* __restrict__ Bpl,
    const float* __restrict__ bias, float* __restrict__ C,
    int M, int N, int Kpad, int Ka)
{
    __shared__ __align__(16) short As[3][128][40];
    __shared__ __align__(16) short Bs[3][128][40];

    const int tid = threadIdx.x;
    const int lane = tid & 63;
    const int wave = tid >> 6;
    const int wm = (wave & 1) * 64, wn = (wave >> 1) * 64;
    const int bm = blockIdx.y * 128, bn = blockIdx.x * 128;
    const int r = tid >> 1;
    const int half = tid & 1;
    const int l15 = lane & 15, q = lane >> 4;
    const size_t PS = (size_t)N * Kpad;

    floatx4 acc[4][4] = {};

    for (int k0 = 0; k0 < Kpad; k0 += 32) {
        {
            float v[16];
            if (AVEC) {
                const float* Ap = A + (size_t)(bm + r) * Ka + k0 + half * 16;
#pragma unroll
                for (int qq = 0; qq < 4; qq++) {
                    float4 f = ((const float4*)Ap)[qq];
                    v[qq * 4 + 0] = f.x; v[qq * 4 + 1] = f.y;
                    v[qq * 4 + 2] = f.z; v[qq * 4 + 3] = f.w;
                }
            } else {
#pragma unroll
                for (int e = 0; e < 16; e++) {
                    int kg = k0 + half * 16 + e;
                    v[e] = (kg < Ka) ? A[(size_t)(bm + r) * Ka + kg] : 0.f;
                }
            }
            unsigned short s[3][16];
#pragma unroll
            for (int e = 0; e < 16; e++)
                split3(v[e], s[0][e], s[1][e], s[2][e]);
#pragma unroll
            for (int p = 0; p < 3; p++) {
                *(short8*)&As[p][r][half * 16]     = *(short8*)&s[p][0];
                *(short8*)&As[p][r][half * 16 + 8] = *(short8*)&s[p][8];
            }
        }
        {
            int n = bn + r;
            short8 z = {0, 0, 0, 0, 0, 0, 0, 0};
#pragma unroll
            for (int p = 0; p < 3; p++) {
                short8 b0 = z, b1 = z;
                if (!NG || n < N) {
                    const unsigned short* bp =
                        Bpl + (size_t)p * PS + (size_t)n * Kpad + k0 + half * 16;
                    b0 = *(const short8*)bp;
                    b1 = *(const short8*)(bp + 8);
                }
                *(short8*)&Bs[p][r][half * 16]     = b0;
                *(short8*)&Bs[p][r][half * 16 + 8] = b1;
            }
        }
        __syncthreads();

        short8 bfr[3][4];
#pragma unroll
        for (int p = 0; p < 3; p++)
#pragma unroll
            for (int ni = 0; ni < 4; ni++)
                bfr[p][ni] = *(short8*)&Bs[p][wn + ni * 16 + l15][q * 8];
#pragma unroll
        for (int pa = 0; pa < 3; pa++) {
            short8 af[4];
#pragma unroll
            for (int mi = 0; mi < 4; mi++)
                af[mi] = *(short8*)&As[pa][wm + mi * 16 + l15][q * 8];
#pragma unroll
            for (int pb = 0; pb < 3; pb++) {
                if (pa + pb > 2) continue;
#pragma unroll
                for (int mi = 0; mi < 4; mi++)
#pragma unroll
                    for (int ni = 0; ni < 4; ni++)
                        acc[mi][ni] = __builtin_amdgcn_mfma_f32_16x16x32_bf16(
                            af[mi], bfr[pb][ni], acc[mi][ni], 0, 0, 0);
            }
        }
        __syncthreads();
    }

#pragma unroll
    for (int ni = 0; ni < 4; ni++) {
        int col = bn + wn + ni * 16 + l15;
        if (NG && col >= N) continue;
        float bv = bias[col];
#pragma unroll
        for (int mi = 0; mi < 4; mi++) {
#pragma unroll
            for (int reg = 0; reg < 4; reg++) {
                int row = bm + wm + mi * 16 + q * 4 + reg;
                C[(size_t)row * N + col] = acc[mi][ni][reg] + bv;
            }
        }
    }
}

// ---------------------------------------------------------------------------
// fp32 fallback GEMM, used only if ws too small for any planes.
// ---------------------------------------------------------------------------
template <bool AVEC, bool NV4>
__global__ __launch_bounds__(256) void gemm128(
    const float* __restrict__ A, const float* __restrict__ B,
    const float* __restrict__ bias, float* __restrict__ C,
    int M, int N, int Keff, int Ktrue, int Ka)
{
    __shared__ __align__(16) float Asm[16][132];
    __shared__ __align__(16) float Bsm[16][132];
    const int tid = threadIdx.x;
    const int bm = blockIdx.y * 128, bn = blockIdx.x * 128;
    const int tx = tid & 15, ty = tid >> 4;
    const int arow = tid >> 2, ac = tid & 3;
    const int bk = tid >> 4, bc = tid & 15;
    float acc[8][8] = {};
    for (int k0 = 0; k0 < Keff; k0 += 16) {
#pragma unroll
        for (int h = 0; h < 2; h++) {
            int rr = arow + h * 64;
            if (AVEC) {
                float4 v = *(const float4*)&A[(size_t)(bm + rr) * Ka + k0 + ac * 4];
                const float* pv = &v.x;
#pragma unroll
                for (int e = 0; e < 4; e++) Asm[ac * 4 + e][rr] = pv[e];
            } else {
#pragma unroll
                for (int e = 0; e < 4; e++) {
                    int kg = k0 + ac * 4 + e;
                    Asm[ac * 4 + e][rr] = (kg < Ka) ? A[(size_t)(bm + rr) * Ka + kg] : 0.f;
                }
            }
        }
        {
            int kg = k0 + bk;
            bool kok = (kg < Ktrue);
#pragma unroll
            for (int h = 0; h < 2; h++) {
                int cc = bc * 4 + h * 64;
                if (NV4) {
                    float4 v = {0.f, 0.f, 0.f, 0.f};
                    if (kok) v = *(const float4*)&B[(size_t)kg * N + bn + cc];
                    *(float4*)&Bsm[bk][cc] = v;
                } else {
#pragma unroll
                    for (int e = 0; e < 4; e++) {
                        int col = bn + cc + e;
                        Bsm[bk][cc + e] = (kok && col < N) ? B[(size_t)kg * N + col] : 0.f;
                    }
                }
            }
        }
        __syncthreads();
#pragma unroll
        for (int k = 0; k < 16; k++) {
            float4 a0 = *(const float4*)&Asm[k][ty * 4];
            float4 a1 = *(const float4*)&Asm[k][ty * 4 + 64];
            float4 b0 = *(const float4*)&Bsm[k][tx * 4];
            float4 b1 = *(const float4*)&Bsm[k][tx * 4 + 64];
            float av[8] = {a0.x, a0.y, a0.z, a0.w, a1.x, a1.y, a1.z, a1.w};
            float bv[8] = {b0.x, b0.y, b0.z, b0.w, b1.x, b1.y, b1.z, b1.w};
#pragma unroll
            for (int i = 0; i < 8; i++)
#pragma unroll
                for (int j = 0; j < 8; j++) acc[i][j] += av[i] * bv[j];
        }
        __syncthreads();
    }
#pragma unroll
    for (int i = 0; i < 8; i++) {
        int row = bm + (i < 4 ? ty * 4 + i : 64 + ty * 4 + (i - 4));
#pragma unroll
        for (int jh = 0; jh < 2; jh++)
#pragma unroll
            for (int e = 0; e < 4; e++) {
                int col = bn + jh * 64 + tx * 4 + e;
                if (NV4 || col < N)
                    C[(size_t)row * N + col] = acc[i][jh * 4 + e] + bias[col];
            }
    }
}

// ---------------------------------------------------------------------------
__global__ __launch_bounds__(256) void colstats_kernel(
    const float* __restrict__ Y, float* __restrict__ part, int N, int rows)
{
    int c = blockIdx.x * 256 + threadIdx.x;
    int r0 = blockIdx.y * rows;
    const float* p = Y + (size_t)r0 * N + c;
    float s = 0.f, s2 = 0.f;
    for (int r = 0; r < rows; r++) {
        float v = p[(size_t)r * N];
        s += v;
        s2 += v * v;
    }
    part[(size_t)(blockIdx.y * 2 + 0) * N + c] = s;
    part[(size_t)(blockIdx.y * 2 + 1) * N + c] = s2;
}

__global__ void finalize_stats_kernel(
    const float* __restrict__ part, const float* __restrict__ g,
    const float* __restrict__ be, float* __restrict__ scale,
    float* __restrict__ shift, int N, int nchunk, float invM)
{
    int c = blockIdx.x * blockDim.x + threadIdx.x;
    if (c >= N) return;
    float s = 0.f, s2 = 0.f;
    for (int i = 0; i < nchunk; i++) {
        s  += part[(size_t)(2 * i + 0) * N + c];
        s2 += part[(size_t)(2 * i + 1) * N + c];
    }
    float m = s * invM;
    float v = s2 * invM - m * m;
    if (v < 0.f) v = 0.f;
    float sc = g[c] / sqrtf(v + 1e-5f);
    scale[c] = sc;
    shift[c] = be[c] - m * sc;
}

// bn-apply; optionally also emits 3 bf16 split planes of the result
__global__ __launch_bounds__(256) void bn_apply_kernel(
    float* __restrict__ Y, const float* __restrict__ scale,
    const float* __restrict__ shift, int do_relu, int n4, int N,
    unsigned short* __restrict__ plane, size_t PS)
{
    int idx = blockIdx.x * 256 + threadIdx.x;
    if (idx >= n4) return;
    float4* Y4 = (float4*)Y;
    float4 v = Y4[idx];
    int c = (idx * 4) & (N - 1);
    v.x = v.x * scale[c + 0] + shift[c + 0];
    v.y = v.y * scale[c + 1] + shift[c + 1];
    v.z = v.z * scale[c + 2] + shift[c + 2];
    v.w = v.w * scale[c + 3] + shift[c + 3];
    if (do_relu) {
        v.x = fmaxf(v.x, 0.f); v.y = fmaxf(v.y, 0.f);
        v.z = fmaxf(v.z, 0.f); v.w = fmaxf(v.w, 0.f);
    }
    Y4[idx] = v;
    if (plane) {
        float vv[4] = {v.x, v.y, v.z, v.w};
        ushortx4 o0, o1, o2;
#pragma unroll
        for (int e = 0; e < 4; e++) {
            unsigned short a, b, cc;
            split3(vv[e], a, b, cc);
            o0[e] = a; o1[e] = b; o2[e] = cc;
        }
        size_t base = (size_t)idx * 4;
        *(ushortx4*)(plane + base) = o0;
        *(ushortx4*)(plane + PS + base) = o1;
        *(ushortx4*)(plane + 2 * PS + base) = o2;
    }
}

__global__ __launch_bounds__(256) void resid_relu_kernel(
    float* __restrict__ Hb, const float* __restrict__ T, int n4,
    unsigned short* __restrict__ plane, size_t PS)
{
    int idx = blockIdx.x * 256 + threadIdx.x;
    if (idx >= n4) return;
    float4 h = ((float4*)Hb)[idx];
    float4 t = ((const float4*)T)[idx];
    h.x = fmaxf(h.x + t.x, 0.f);
    h.y = fmaxf(h.y + t.y, 0.f);
    h.z = fmaxf(h.z + t.z, 0.f);
    h.w = fmaxf(h.w + t.w, 0.f);
    ((float4*)Hb)[idx] = h;
    if (plane) {
        float vv[4] = {h.x, h.y, h.z, h.w};
        ushortx4 o0, o1, o2;
#pragma unroll
        for (int e = 0; e < 4; e++) {
            unsigned short a, b, cc;
            split3(vv[e], a, b, cc);
            o0[e] = a; o1[e] = b; o2[e] = cc;
        }
        size_t base = (size_t)idx * 4;
        *(ushortx4*)(plane + base) = o0;
        *(ushortx4*)(plane + PS + base) = o1;
        *(ushortx4*)(plane + 2 * PS + base) = o2;
    }
}

// ---------------------------------------------------------------------------
// O = det(R)*R, R = polar(M). Jacobi on M^T M in fp64. fp32 output.
// ---------------------------------------------------------------------------
__global__ __launch_bounds__(256) void svd_kernel(
    const float* __restrict__ O3, float* __restrict__ out, int nb)
{
    int gidx = blockIdx.x * 256 + threadIdx.x;
    if (gidx >= nb * 24) return;
    int row = gidx / 24;
    int j = gidx - row * 24;
    const float* rowp = O3 + (size_t)row * 226;
    const float* src = rowp + j * 9;

    double m[3][3];
#pragma unroll
    for (int r = 0; r < 3; r++)
#pragma unroll
        for (int c = 0; c < 3; c++) m[r][c] = (double)src[r * 3 + c];

    double a[3][3];
#pragma unroll
    for (int r = 0; r < 3; r++)
#pragma unroll
        for (int c = 0; c < 3; c++) {
            double s = 0.0;
#pragma unroll
            for (int k = 0; k < 3; k++) s += m[k][r] * m[k][c];
            a[r][c] = s;
        }

    double V[3][3] = {{1, 0, 0}, {0, 1, 0}, {0, 0, 1}};
    const int PP[3] = {0, 0, 1}, QQ[3] = {1, 2, 2};
    for (int sweep = 0; sweep < 8; sweep++) {
        for (int r3 = 0; r3 < 3; r3++) {
            int p = PP[r3], q = QQ[r3];
            double apq = a[p][q];
            if (fabs(apq) < 1e-60) continue;
            double tau = (a[q][q] - a[p][p]) / (2.0 * apq);
            double t = ((tau >= 0.0) ? 1.0 : -1.0) / (fabs(tau) + sqrt(1.0 + tau * tau));
            double c = 1.0 / sqrt(1.0 + t * t);
            double s = t * c;
#pragma unroll
            for (int k = 0; k < 3; k++) {
                double xp = a[p][k], xq = a[q][k];
                a[p][k] = c * xp - s * xq;
                a[q][k] = s * xp + c * xq;
            }
#pragma unroll
            for (int k = 0; k < 3; k++) {
                double xp = a[k][p], xq = a[k][q];
                a[k][p] = c * xp - s * xq;
                a[k][q] = s * xp + c * xq;
            }
#pragma unroll
            for (int k = 0; k < 3; k++) {
                double xp = V[k][p], xq = V[k][q];
                V[k][p] = c * xp - s * xq;
                V[k][q] = s * xp + c * xq;
            }
        }
    }

    double lam[3] = {a[0][0], a[1][1], a[2][2]};
    int i3 = 0;
    if (lam[1] < lam[i3]) i3 = 1;
    if (lam[2] < lam[i3]) i3 = 2;
    int i1 = (i3 + 1) % 3, i2 = (i3 + 2) % 3;

    double v1[3], v2[3], v3[3];
#pragma unroll
    for (int k = 0; k < 3; k++) {
        v1[k] = V[k][i1];
        v2[k] = V[k][i2];
        v3[k] = V[k][i3];
    }

    double u1[3], u2[3];
#pragma unroll
    for (int r = 0; r < 3; r++)
        u1[r] = m[r][0] * v1[0] + m[r][1] * v1[1] + m[r][2] * v1[2];
    double n1 = sqrt(u1[0] * u1[0] + u1[1] * u1[1] + u1[2] * u1[2]);
    double inv1 = (n1 > 1e-150) ? 1.0 / n1 : 0.0;
#pragma unroll
    for (int r = 0; r < 3; r++) u1[r] *= inv1;

#pragma unroll
    for (int r = 0; r < 3; r++)
        u2[r] = m[r][0] * v2[0] + m[r][1] * v2[1] + m[r][2] * v2[2];
    double d12 = u1[0] * u2[0] + u1[1] * u2[1] + u1[2] * u2[2];
#pragma unroll
    for (int r = 0; r < 3; r++) u2[r] -= d12 * u1[r];
    double n2 = sqrt(u2[0] * u2[0] + u2[1] * u2[1] + u2[2] * u2[2]);
    double inv2 = (n2 > 1e-150) ? 1.0 / n2 : 0.0;
#pragma unroll
    for (int r = 0; r < 3; r++) u2[r] *= inv2;

    double detM = m[0][0] * (m[1][1] * m[2][2] - m[1][2] * m[2][1])
                - m[0][1] * (m[1][0] * m[2][2] - m[1][2] * m[2][0])
                + m[0][2] * (m[1][0] * m[2][1] - m[1][1] * m[2][0]);
    double sgn = (detM >= 0.0) ? 1.0 : -1.0;
    double detV = v1[0] * (v2[1] * v3[2] - v2[2] * v3[1])
                - v1[1] * (v2[0] * v3[2] - v2[2] * v3[0])
                + v1[2] * (v2[0] * v3[1] - v2[1] * v3[0]);
    double sv = (detV >= 0.0) ? 1.0 : -1.0;

    double u3[3];
    u3[0] = sgn * sv * (u1[1] * u2[2] - u1[2] * u2[1]);
    u3[1] = sgn * sv * (u1[2] * u2[0] - u1[0] * u2[2]);
    u3[2] = sgn * sv * (u1[0] * u2[1] - u1[1] * u2[0]);

    size_t rot_base = (size_t)gidx * 9;
    size_t beta_base = (size_t)nb * 24 * 9 + (size_t)row * 10;
#pragma unroll
    for (int r = 0; r < 3; r++)
#pragma unroll
        for (int c = 0; c < 3; c++)
            out[rot_base + r * 3 + c] =
                (float)(sgn * (u1[r] * v1[c] + u2[r] * v2[c] + u3[r] * v3[c]));

    if (j < 10) out[beta_base + j] = rowp[216 + j];
}

// ---------------------------------------------------------------------------
extern "C" void kernel_launch(void* const* d_in, const int* in_sizes, int n_in,
                              void* d_out, int out_size, void* d_ws, size_t ws_size,
                              hipStream_t stream)
{
    const float* x    = (const float*)d_in[0];
    const float* W0   = (const float*)d_in[1];
    const float* b0   = (const float*)d_in[2];
    const float* g0   = (const float*)d_in[3];
    const float* be0  = (const float*)d_in[4];
    const float* W1a  = (const float*)d_in[5];
    const float* b1a  = (const float*)d_in[6];
    const float* g1a  = (const float*)d_in[7];
    const float* be1a = (const float*)d_in[8];
    const float* W1b  = (const float*)d_in[9];
    const float* b1b  = (const float*)d_in[10];
    const float* g1b  = (const float*)d_in[11];
    const float* be1b = (const float*)d_in[12];
    const float* W2a  = (const float*)d_in[13];
    const float* b2a  = (const float*)d_in[14];
    const float* g2a  = (const float*)d_in[15];
    const float* be2a = (const float*)d_in[16];
    const float* W2b  = (const float*)d_in[17];
    const float* b2b  = (const float*)d_in[18];
    const float* g2b  = (const float*)d_in[19];
    const float* be2b = (const float*)d_in[20];
    const float* W3   = (const float*)d_in[21];
    const float* b3   = (const float*)d_in[22];

    const int M = 8192, H = 1024, K0 = 5169, K0P = 5184, NO = 226, NOP = 256;
    const int NCHUNK = 32;

    const size_t SZ_ACT  = (size_t)M * H;
    const size_t SZ_O3   = (size_t)M * NO;
    const size_t SZ_PART = (size_t)2 * NCHUNK * H;

    float* ws   = (float*)d_ws;
    float* buf0 = ws;
    float* buf1 = buf0 + SZ_ACT;
    float* buf2 = buf1 + SZ_ACT;
    float* buf3 = buf2 + SZ_ACT;
    float* part = buf3 + SZ_O3;
    float* scale = part + SZ_PART;
    float* shift = scale + H;
    size_t float_base = 3 * SZ_ACT + SZ_O3 + SZ_PART + 2 * H + 16;

    // bf16 weight planes (3 per weight), [Nalloc][Kpad]
    unsigned short* pl = (unsigned short*)(ws + float_base);
    unsigned short* w0p  = pl;
    unsigned short* w1ap = w0p  + (size_t)3 * H * K0P;
    unsigned short* w1bp = w1ap + (size_t)3 * H * H;
    unsigned short* w2ap = w1bp + (size_t)3 * H * H;
    unsigned short* w2bp = w2ap + (size_t)3 * H * H;
    unsigned short* w3p  = w2bp + (size_t)3 * H * H;
    // new-path extras: activation planes
    unsigned short* xp  = w3p + (size_t)3 * NOP * H;
    unsigned short* a0p = xp  + (size_t)3 * M * K0P;
    unsigned short* a1p = a0p + (size_t)3 * M * H;
    unsigned short* pend_new = a1p + (size_t)3 * M * H;
    unsigned short* pend_old = w3p + (size_t)3 * NO * H;

    size_t bytes_new = float_base * 4 + (size_t)(pend_new - pl) * 2;
    size_t bytes_old = float_base * 4 + (size_t)(pend_old - pl) * 2;
    bool use_new = ws_size >= bytes_new;
    bool use_old = !use_new && ws_size >= bytes_old;

    dim3 blk(256);
    const int n4 = M * H / 4;
    const size_t PSH = (size_t)M * H;

    auto bnstep = [&](float* Y, const float* g, const float* be, int relu,
                      unsigned short* plane) {
        colstats_kernel<<<dim3(H / 256, NCHUNK), blk, 0, stream>>>(Y, part, H, M / NCHUNK);
        finalize_stats_kernel<<<dim3(H / 256), blk, 0, stream>>>(part, g, be, scale, shift, H, NCHUNK, 1.0f / M);
        bn_apply_kernel<<<dim3(n4 / 256), blk, 0, stream>>>(Y, scale, shift, relu, n4, H, plane, PSH);
    };

    if (use_new) {
        // 1. weight planes (w3 padded to NOP rows, zero-filled)
        wsplit_kernel<<<dim3(K0P / 32, H / 32), blk, 0, stream>>>(W0, w0p, K0, K0P, H, H);
        wsplit_kernel<<<dim3(H / 32, H / 32), blk, 0, stream>>>(W1a, w1ap, H, H, H, H);
        wsplit_kernel<<<dim3(H / 32, H / 32), blk, 0, stream>>>(W1b, w1bp, H, H, H, H);
        wsplit_kernel<<<dim3(H / 32, H / 32), blk, 0, stream>>>(W2a, w2ap, H, H, H, H);
        wsplit_kernel<<<dim3(H / 32, H / 32), blk, 0, stream>>>(W2b, w2bp, H, H, H, H);
        wsplit_kernel<<<dim3(H / 32, NOP / 32), blk, 0, stream>>>(W3, w3p, H, H, NO, NOP);
        // 2. input planes
        asplit_kernel<<<dim3(M * (K0P / 4) / 256), blk, 0, stream>>>(x, xp, K0, K0P, M);

        dim3 gH(H / 128, M / 128);     // 512 blocks
        dim3 gO(NOP / 128, M / 128);   // 128 blocks

        // 3. layer 0
        mfma_gemm2<<<gH, blk, 0, stream>>>(xp, w0p, b0, buf0, M, H, K0P, H);
        bnstep(buf0, g0, be0, 1, a0p);
        // 4. block 1
        mfma_gemm2<<<gH, blk, 0, stream>>>(a0p, w1ap, b1a, buf1, M, H, H, H);
        bnstep(buf1, g1a, be1a, 1, a1p);
        mfma_gemm2<<<gH, blk, 0, stream>>>(a1p, w1bp, b1b, buf2, M, H, H, H);
        bnstep(buf2, g1b, be1b, 0, nullptr);
        resid_relu_kernel<<<dim3(n4 / 256), blk, 0, stream>>>(buf0, buf2, n4, a0p, PSH);
        // 5. block 2
        mfma_gemm2<<<gH, blk, 0, stream>>>(a0p, w2ap, b2a, buf1, M, H, H, H);
        bnstep(buf1, g2a, be2a, 1, a1p);
        mfma_gemm2<<<gH, blk, 0, stream>>>(a1p, w2bp, b2b, buf2, M, H, H, H);
        bnstep(buf2, g2b, be2b, 0, nullptr);
        resid_relu_kernel<<<dim3(n4 / 256), blk, 0, stream>>>(buf0, buf2, n4, a0p, PSH);
        // 6. final linear (B planes padded to 256 rows; C guarded to N=226)
        mfma_gemm2<<<gO, blk, 0, stream>>>(a0p, w3p, b3, buf3, M, NO, H, NOP);
    } else if (use_old) {
        // previous-session path (split-in-GEMM)
        wsplit_kernel<<<dim3(K0P / 32, H / 32), blk, 0, stream>>>(W0, w0p, K0, K0P, H, H);
        wsplit_kernel<<<dim3(H / 32, H / 32), blk, 0, stream>>>(W1a, w1ap, H, H, H, H);
        wsplit_kernel<<<dim3(H / 32, H / 32), blk, 0, stream>>>(W1b, w1bp, H, H, H, H);
        wsplit_kernel<<<dim3(H / 32, H / 32), blk, 0, stream>>>(W2a, w2ap, H, H, H, H);
        wsplit_kernel<<<dim3(H / 32, H / 32), blk, 0, stream>>>(W2b, w2bp, H, H, H, H);
        wsplit_kernel<<<dim3(H / 32, (NO + 31) / 32), blk, 0, stream>>>(W3, w3p, H, H, NO, NO);

        dim3 gH(H / 128, M / 128);
        dim3 gO((NO + 127) / 128, M / 128);

        mfma_gemm<false, false><<<gH, blk, 0, stream>>>(x, w0p, b0, buf0, M, H, K0P, K0);
        bnstep(buf0, g0, be0, 1, nullptr);
        mfma_gemm<true, false><<<gH, blk, 0, stream>>>(buf0, w1ap, b1a, buf1, M, H, H, H);
        bnstep(buf1, g1a, be1a, 1, nullptr);
        mfma_gemm<true, false><<<gH, blk, 0, stream>>>(buf1, w1bp, b1b, buf2, M, H, H, H);
        bnstep(buf2, g1b, be1b, 0, nullptr);
        resid_relu_kernel<<<dim3(n4 / 256), blk, 0, stream>>>(buf0, buf2, n4, nullptr, 0);
        mfma_gemm<true, false><<<gH, blk, 0, stream>>>(buf0, w2ap, b2a, buf1, M, H, H, H);
        bnstep(buf1, g2a, be2a, 1, nullptr);
        mfma_gemm<true, false><<<gH, blk, 0, stream>>>(buf1, w2bp, b2b, buf2, M, H, H, H);
        bnstep(buf2, g2b, be2b, 0, nullptr);
        resid_relu_kernel<<<dim3(n4 / 256), blk, 0, stream>>>(buf0, buf2, n4, nullptr, 0);
        mfma_gemm<true, true><<<gO, blk, 0, stream>>>(buf0, w3p, b3, buf3, M, NO, H, H);
    } else {
        // fp32 fallback
        dim3 gH(H / 128, M / 128);
        dim3 gO((NO + 127) / 128, M / 128);
        gemm128<false, true><<<gH, blk, 0, stream>>>(x, W0, b0, buf0, M, H, K0P, K0, K0);
        bnstep(buf0, g0, be0, 1, nullptr);
        gemm128<true, true><<<gH, blk, 0, stream>>>(buf0, W1a, b1a, buf1, M, H, H, H, H);
        bnstep(buf1, g1a, be1a, 1, nullptr);
        gemm128<true, true><<<gH, blk, 0, stream>>>(buf1, W1b, b1b, buf2, M, H, H, H, H);
        bnstep(buf2, g1b, be1b, 0, nullptr);
        resid_relu_kernel<<<dim3(n4 / 256), blk, 0, stream>>>(buf0, buf2, n4, nullptr, 0);
        gemm128<true, true><<<gH, blk, 0, stream>>>(buf0, W2a, b2a, buf1, M, H, H, H, H);
        bnstep(buf1, g2a, be2a, 1, nullptr);
        gemm128<true, true><<<gH, blk, 0, stream>>>(buf1, W2b, b2b, buf2, M, H, H, H, H);
        bnstep(buf2, g2b, be2b, 0, nullptr);
        resid_relu_kernel<<<dim3(n4 / 256), blk, 0, stream>>>(buf0, buf2, n4, nullptr, 0);
        gemm128<true, false><<<gO, blk, 0, stream>>>(buf0, W3, b3, buf3, M, NO, H, H, H);
    }

    // SVD epilogue -> d_out (fp32: rotmat then betas)
    svd_kernel<<<dim3((M * 24 + 255) / 256), blk, 0, stream>>>(buf3, (float*)d_out, M);
}